// Round 11
// baseline (104.857 us; speedup 1.0000x reference)
//
#include <hip/hip_runtime.h>

// LoRA forward: out = (h @ B^T) @ A^T, h: (16384, 4096) f32, rank 16.
// R11: single fused kernel = R10-K1 (bf16 MFMA, wave-private LDS staging,
// counted vmcnt, no barriers in k-loop) + R10-K2 (A-frag VGPRs, NT stores)
// appended per block. hr lives in LDS only; no device-wide phase sync.

constexpr int  D  = 4096;
constexpr int  RK = 16;
constexpr long M  = 16384;

typedef float f32x4 __attribute__((ext_vector_type(4)));
typedef short bf16x8 __attribute__((ext_vector_type(8)));
typedef int   i32x4 __attribute__((ext_vector_type(4)));

__device__ __forceinline__ void gload_lds16(const float* src, float* ldsdst) {
  __builtin_amdgcn_global_load_lds(
      (const __attribute__((address_space(1))) void*)src,
      (__attribute__((address_space(3))) void*)ldsdst, 16, 0, 0);
}

__device__ __forceinline__ float dot4(float4 a, float4 b) {
  return a.x * b.x + a.y * b.y + a.z * b.z + a.w * b.w;
}

__device__ __forceinline__ unsigned cvt_pk_bf16(float lo, float hi) {
  unsigned r;
  asm("v_cvt_pk_bf16_f32 %0, %1, %2" : "=v"(r) : "v"(lo), "v"(hi));
  return r;
}

__device__ __forceinline__ bf16x8 to_bf16x8(float4 a, float4 b) {
  i32x4 u;
  u.x = (int)cvt_pk_bf16(a.x, a.y);
  u.y = (int)cvt_pk_bf16(a.z, a.w);
  u.z = (int)cvt_pk_bf16(b.x, b.y);
  u.w = (int)cvt_pk_bf16(b.z, b.w);
  return __builtin_bit_cast(bf16x8, u);
}

// Block = 32 rows. Wave w: row-tile t=w&1 (16 rows), k-half q=w>>1 (2048).
constexpr int KC   = 32;            // k per chunk (one MFMA)
constexpr int NCH1 = 2048 / KC;     // 64 chunks per wave

__global__ __launch_bounds__(256, 4) void lora_fused(
    const float* __restrict__ h,
    const float* __restrict__ matA,   // (D, RK) row-major
    const float* __restrict__ matB,   // (RK, D) row-major
    float* __restrict__ out) {
  __shared__ float sH[4][4][16][KC];  // [wave][ringbuf][row][k] 32 KB
  __shared__ float part[4][16][RK];   // [wave][row][rank]        4 KB
  __shared__ float hrs[32][RK];       // reduced hr               2 KB

  const int tid = threadIdx.x;
  const int wu  = __builtin_amdgcn_readfirstlane(tid >> 6);  // wave 0..3
  const int l   = tid & 63;
  const int t   = wu & 1;             // row-tile
  const int q   = wu >> 1;            // k-half
  const long rbase = (long)blockIdx.x * 32;
  const long rowt  = rbase + t * 16;
  const int  k0    = q * 2048;

  // ================= Phase 1: hr = h @ B^T (MFMA) ==========================
  auto STAGE = [&](int b, int c) {
#pragma unroll
    for (int ld = 0; ld < 2; ++ld) {
      const int R  = ld * 8 + (l >> 3);
      const int sd = l & 7;
      const float* src =
          h + (rowt + R) * (long)D + k0 + c * KC + ((sd ^ (R & 7)) * 4);
      gload_lds16(src, &sH[wu][b][ld * 8][0]);
    }
  };
  auto BLOAD = [&](int c, float4& b0, float4& b1) {
    const float* bp = matB + (long)(l & 15) * D + k0 + c * KC + (l >> 4) * 8;
    b0 = *reinterpret_cast<const float4*>(bp);
    b1 = *reinterpret_cast<const float4*>(bp + 4);
  };

  f32x4 acc = {0.f, 0.f, 0.f, 0.f};
  float4 bc0, bc1, bn0, bn1;

  STAGE(0, 0);
  BLOAD(0, bc0, bc1);
  STAGE(1, 1);

#pragma unroll 1
  for (int c = 0; c < NCH1; ++c) {
    const int cb = (c + 1 < NCH1) ? c + 1 : NCH1 - 1;   // clamped prefetch
    const int cs = (c + 2 < NCH1) ? c + 2 : NCH1 - 1;
    BLOAD(cb, bn0, bn1);            // B(c+1): 2 loads
    STAGE((c + 2) & 3, cs);         // h(c+2): 2 loads
    // queue: h(c),B(c),h(c+1),B(c+1),h(c+2) = 10 outstanding.
    asm volatile("s_waitcnt vmcnt(6)" ::: "memory");
    __builtin_amdgcn_sched_barrier(0);

    const float* abase = &sH[wu][c & 3][l & 15][0];
    const int sj = (l >> 4) * 2, r7 = l & 7;
    const float4 a0 =
        *reinterpret_cast<const float4*>(abase + ((sj ^ r7) * 4));
    const float4 a1 =
        *reinterpret_cast<const float4*>(abase + (((sj + 1) ^ r7) * 4));

    const bf16x8 af = to_bf16x8(a0, a1);
    const bf16x8 bf = to_bf16x8(bc0, bc1);
    acc = __builtin_amdgcn_mfma_f32_16x16x32_bf16(af, bf, acc, 0, 0, 0);

    bc0 = bn0;
    bc1 = bn1;
  }

  asm volatile("s_waitcnt vmcnt(0)" ::: "memory");
  // C/D layout: col(rank) = l&15, row = (l>>4)*4 + j
#pragma unroll
  for (int j = 0; j < 4; ++j) part[wu][(l >> 4) * 4 + j][l & 15] = acc[j];
  __syncthreads();

  // reduce the two k-halves: tile0 = waves {0,2}, tile1 = waves {1,3}
#pragma unroll
  for (int e = tid; e < 512; e += 256) {
    const int row = e >> 4, rk = e & 15, tl = row >> 4;
    hrs[row][rk] = part[tl][row & 15][rk] + part[tl + 2][row & 15][rk];
  }
  __syncthreads();

  // ================= Phase 2: out = hr @ A^T (per-block, no global sync) ===
#pragma unroll 1
  for (int cs2 = 0; cs2 < 4; ++cs2) {
    const int c0 = cs2 * 1024 + tid * 4;   // 4 contiguous cols per thread
    float4 a[4][4];                        // A rows for my 4 cols (L2-hot)
#pragma unroll
    for (int j = 0; j < 4; ++j)
#pragma unroll
      for (int qq = 0; qq < 4; ++qq)
        a[j][qq] = *reinterpret_cast<const float4*>(
            matA + (long)(c0 + j) * RK + qq * 4);

#pragma unroll 4
    for (int row = 0; row < 32; ++row) {
      const float4* hv = reinterpret_cast<const float4*>(&hrs[row][0]);
      const float4 h0 = hv[0], h1 = hv[1], h2 = hv[2], h3 = hv[3];
      f32x4 o;
      o.x = dot4(h0, a[0][0]) + dot4(h1, a[0][1]) + dot4(h2, a[0][2]) +
            dot4(h3, a[0][3]);
      o.y = dot4(h0, a[1][0]) + dot4(h1, a[1][1]) + dot4(h2, a[1][2]) +
            dot4(h3, a[1][3]);
      o.z = dot4(h0, a[2][0]) + dot4(h1, a[2][1]) + dot4(h2, a[2][2]) +
            dot4(h3, a[2][3]);
      o.w = dot4(h0, a[3][0]) + dot4(h1, a[3][1]) + dot4(h2, a[3][2]) +
            dot4(h3, a[3][3]);
      __builtin_nontemporal_store(
          o, reinterpret_cast<f32x4*>(out + (rbase + row) * (long)D + c0));
    }
  }
}

extern "C" void kernel_launch(void* const* d_in, const int* in_sizes, int n_in,
                              void* d_out, int out_size, void* d_ws,
                              size_t ws_size, hipStream_t stream) {
  const float* h    = (const float*)d_in[0];
  const float* matA = (const float*)d_in[1];
  const float* matB = (const float*)d_in[2];
  float* out        = (float*)d_out;

  hipLaunchKernelGGL(lora_fused, dim3((int)(M / 32)), dim3(256), 0, stream,
                     h, matA, matB, out);
}